// Round 9
// baseline (293.050 us; speedup 1.0000x reference)
//
#include <hip/hip_runtime.h>

// cAttention B=8, C=16, L=512, D=256 (fp32 in/out).
// R13 (RESUBMIT after infra failure: "MI355X container failed twice" --
// no counters came back; kernel unchanged to preserve the A/B vs R10).
// R13 = R10 EXACT revert (best: 83us fused) + two pressure-neutral tweaks:
//   - s_setprio(1/0) around the fused-phase MFMA quad (barrier-free phase
//     with wave role diversity = T5-positive regime; R11's try was
//     confounded by a register spill).
//   - v_cvt_pk_bf16_f32 for the xs fp32->bf16 convert (halves prologue insts).
// Frozen decisions (two failed rounds): score stays scalar-f32
// rcp(1+eq*ek); Es stays full-exponent e^{2z} (f16, clamp +-15 on 2z).
// R11 lesson: batched-rcp spilled (WRITE 65->408MB). R12 lesson: packed-f16
// score front-end costs +18us despite fewer ops (scheduling vs MFMA).

typedef __attribute__((ext_vector_type(8))) short bf16x8;
typedef __attribute__((ext_vector_type(4))) float f32x4;
typedef __attribute__((ext_vector_type(8))) _Float16 h16x8;
typedef __attribute__((ext_vector_type(4))) _Float16 h16x4;
typedef const __attribute__((address_space(1))) void* gp1_t;
typedef __attribute__((address_space(3))) void* lp3_t;

__device__ __forceinline__ unsigned short f2bf(float f) {
  union { float f; unsigned int u; } v; v.f = f;
  return (unsigned short)((v.u + 0x7FFFu + ((v.u >> 16) & 1u)) >> 16);
}

__device__ __forceinline__ unsigned int cvt_pk_bf16(float a, float b) {
  unsigned int r;
  asm("v_cvt_pk_bf16_f32 %0, %1, %2" : "=v"(r) : "v"(a), "v"(b));
  return r;  // lo = bf16(a), hi = bf16(b)
}

// ---- prep: Wqb_t = transpose-pack(Wqkv[0:512]) ; Wcb_t = pack(Wout @ Wv) ;
//      bcomb = Wout @ bv.  Layout: W_t[k>>3][n][8] (8 consecutive k per 16B). ----
__global__ __launch_bounds__(256) void ca_prep_kernel(
    const float* __restrict__ Wqkv, const float* __restrict__ Wout,
    const float* __restrict__ bqkv,
    unsigned short* __restrict__ Wqb_t, unsigned short* __restrict__ Wcb_t,
    float* __restrict__ bcomb) {
  const int blk = blockIdx.x;
  if (blk < 64) {
    // convert+transpose Wqkv (512x256 f32) -> Wqb_t[k8][512][8] bf16
    const int t = blk * 256 + threadIdx.x;  // 16384 threads
    const int k8 = t >> 9, n = t & 511;
    const float* src = Wqkv + (size_t)n * 256 + k8 * 8;
    const float4 v0 = *(const float4*)src;
    const float4 v1 = *(const float4*)(src + 4);
    bf16x8 o;
    o[0] = (short)f2bf(v0.x); o[1] = (short)f2bf(v0.y);
    o[2] = (short)f2bf(v0.z); o[3] = (short)f2bf(v0.w);
    o[4] = (short)f2bf(v1.x); o[5] = (short)f2bf(v1.y);
    o[6] = (short)f2bf(v1.z); o[7] = (short)f2bf(v1.w);
    *(bf16x8*)(Wqb_t + (size_t)t * 8) = o;  // t = k8*512 + n: coalesced store
    return;
  }
  const int dp = blk - 64;       // output row n (0..255)
  const int e = threadIdx.x;     // k (0..255)
  const float* wrow = Wout + (size_t)dp * 256;
  float acc = 0.f;
  for (int f = 0; f < 256; ++f)
    acc = fmaf(wrow[f], Wqkv[(size_t)(512 + f) * 256 + e], acc);
  Wcb_t[((size_t)(e >> 3) * 256 + dp) * 8 + (e & 7)] = f2bf(acc);
  if (e == 0) {
    float b = 0.f;
    for (int f = 0; f < 256; ++f) b = fmaf(wrow[f], bqkv[512 + f], b);
    bcomb[dp] = b;
  }
}

// ---- fused: qk MFMA + exp + (score || out MFMA) + softmax diag ----
__global__ __launch_bounds__(512, 6) void ca_fused(
    const float* __restrict__ x,               // (8,16,512,256) fp32
    const unsigned short* __restrict__ Wqb_t,  // [32][512][8] bf16
    const unsigned short* __restrict__ Wcb_t,  // [32][256][8] bf16
    const float* __restrict__ bqkv, const float* __restrict__ bh,
    const float* __restrict__ Vw,
    const float* __restrict__ bcomb, const float* __restrict__ bout,
    float* __restrict__ out) {
  __shared__ __align__(16) unsigned short xs[32 * 264];  // 16.9 KB A tile
  __shared__ __align__(16) unsigned short BsEs[16640];   // 33.3 KB: Bs / Es alias
  __shared__ __align__(16) float vw_s[256];
  __shared__ float af_s[32];
  unsigned short* const Bs = BsEs;          // stage1 staging
  _Float16* const Es = (_Float16*)BsEs;     // 32 rows x 520 (512 + pad)

  const int tid = threadIdx.x;
  const int lane = tid & 63, wave = tid >> 6;
  const int quad = lane >> 4, l15 = lane & 15;
  const int rt0 = blockIdx.x * 32;          // global xf row base

  if (tid < 256) vw_s[tid] = -2.f * Vw[tid];

  // issue stage1 k0c=0 B loads (2048 x 16B segs, lane-linear into Bs)
#pragma unroll
  for (int i = 0; i < 4; ++i) {
    const int sb = wave * 256 + i * 64;
    const unsigned short* g = Wqb_t + (size_t)(sb + lane) * 8;
    __builtin_amdgcn_global_load_lds((gp1_t)g, (lp3_t)(Bs + sb * 8), 16, 0, 0);
  }

  // x tile: 32 rows x 256 fp32 -> bf16 -> xs (row stride 264: 2-way-free reads)
  {
    const int rl = tid >> 4, c0 = (tid & 15) * 16;
    const int r = rt0 + rl;
    const int b = r >> 13, l = (r >> 4) & 511, c = r & 15;
    const float* src = x + ((size_t)(b * 16 + c) * 512 + l) * 256 + c0;
    unsigned short* dst = xs + rl * 264 + c0;
#pragma unroll
    for (int j = 0; j < 2; ++j) {
      const float4 v0 = *(const float4*)(src + j * 8);
      const float4 v1 = *(const float4*)(src + j * 8 + 4);
      uint4 o;
      o.x = cvt_pk_bf16(v0.x, v0.y);
      o.y = cvt_pk_bf16(v0.z, v0.w);
      o.z = cvt_pk_bf16(v1.x, v1.y);
      o.w = cvt_pk_bf16(v1.z, v1.w);
      *(uint4*)(dst + j * 8) = o;
    }
  }
  __syncthreads();  // xs ready; k0c=0 B tile landed (barrier drains vmcnt)

  // ---------- stage 1: E[32 x 512] ----------
  f32x4 acc[2][4] = {};
  for (int k0c = 0; k0c < 8; ++k0c) {
    bf16x8 af[2], bfr[4];
#pragma unroll
    for (int mi = 0; mi < 2; ++mi)
      af[mi] = *(const bf16x8*)&xs[(mi * 16 + l15) * 264 + k0c * 32 + quad * 8];
#pragma unroll
    for (int ni = 0; ni < 4; ++ni)
      bfr[ni] = *(const bf16x8*)&Bs[(quad * 512 + wave * 64 + ni * 16 + l15) * 8];
    __syncthreads();  // frags in regs; Bs free for next tile
    if (k0c < 7) {
#pragma unroll
      for (int i = 0; i < 4; ++i) {
        const int sb = wave * 256 + i * 64;
        const unsigned short* g =
            Wqb_t + ((size_t)(k0c + 1) * 2048 + sb + lane) * 8;
        __builtin_amdgcn_global_load_lds((gp1_t)g, (lp3_t)(Bs + sb * 8), 16, 0, 0);
      }
    }
#pragma unroll
    for (int mi = 0; mi < 2; ++mi)
#pragma unroll
      for (int ni = 0; ni < 4; ++ni)
        acc[mi][ni] = __builtin_amdgcn_mfma_f32_16x16x32_bf16(
            bfr[ni], af[mi], acc[mi][ni], 0, 0, 0);
    __syncthreads();  // drains vmcnt: next tile ready
  }

  // stage-1 epilogue: E = exp2(clamp((acc+bias)*2log2e, +-15)) -> Es (over Bs)
  const float SC = 2.8853900817779268f;  // 2*log2(e)
  const bool isq = (wave < 4);           // n < 256 -> q part (gets bh)
#pragma unroll
  for (int mi = 0; mi < 2; ++mi) {
    const int rl = mi * 16 + l15;
#pragma unroll
    for (int ni = 0; ni < 4; ++ni) {
      const int n = wave * 64 + ni * 16 + quad * 4;
      const float4 bq = *(const float4*)(bqkv + n);
      float4 bhv = make_float4(0.f, 0.f, 0.f, 0.f);
      if (isq) bhv = *(const float4*)(bh + n);
      h16x4 st;
      st[0] = (_Float16)__builtin_amdgcn_exp2f(
          fminf(15.f, fmaxf(-15.f, (acc[mi][ni][0] + bq.x + bhv.x) * SC)));
      st[1] = (_Float16)__builtin_amdgcn_exp2f(
          fminf(15.f, fmaxf(-15.f, (acc[mi][ni][1] + bq.y + bhv.y) * SC)));
      st[2] = (_Float16)__builtin_amdgcn_exp2f(
          fminf(15.f, fmaxf(-15.f, (acc[mi][ni][2] + bq.z + bhv.z) * SC)));
      st[3] = (_Float16)__builtin_amdgcn_exp2f(
          fminf(15.f, fmaxf(-15.f, (acc[mi][ni][3] + bq.w + bhv.w) * SC)));
      *(h16x4*)&Es[rl * 520 + n] = st;
    }
  }
  __syncthreads();  // Es visible to all waves

  // ---------- fused: score (VALU) || stage 2 (MFMA + L2 B-fetch) ----------
  f32x4 acc2[2][2] = {};
  {
    const int p = tid >> 8, qc = (tid >> 4) & 15, kc = tid & 15;
    const _Float16* eqp = Es + (p * 16 + qc) * 520;
    const _Float16* ekp = Es + (p * 16 + kc) * 520 + 256;
    const unsigned short* wb2 = Wcb_t + (size_t)(quad * 256 + wave * 32 + l15) * 8;
    bf16x8 bcur0 = *(const bf16x8*)(wb2);
    bf16x8 bcur1 = *(const bf16x8*)(wb2 + 128);
    f32x4 a4 = {};
#pragma unroll
    for (int c = 0; c < 8; ++c) {
      bf16x8 bnxt0, bnxt1;
      if (c < 7) {  // prefetch next chunk's B-frags (covered by score VALU)
        bnxt0 = *(const bf16x8*)(wb2 + (size_t)(c + 1) * 8192);
        bnxt1 = *(const bf16x8*)(wb2 + (size_t)(c + 1) * 8192 + 128);
      }
      bf16x8 af0 = *(const bf16x8*)&xs[l15 * 264 + c * 32 + quad * 8];
      bf16x8 af1 = *(const bf16x8*)&xs[(16 + l15) * 264 + c * 32 + quad * 8];
      // 4 score iterations over d = 32c .. 32c+31 (scalar-f32 form: frozen)
#pragma unroll
      for (int j = 0; j < 4; ++j) {
        const int d = c * 32 + j * 8;
        const h16x8 eq = *(const h16x8*)(eqp + d);
        const h16x8 ek = *(const h16x8*)(ekp + d);
        const f32x4 wv0 = *(const f32x4*)(vw_s + d);
        const f32x4 wv1 = *(const f32x4*)(vw_s + d + 4);
        f32x4 sg0, sg1;
        sg0.x = __builtin_amdgcn_rcpf(1.f + (float)eq[0] * (float)ek[0]);
        sg0.y = __builtin_amdgcn_rcpf(1.f + (float)eq[1] * (float)ek[1]);
        sg0.z = __builtin_amdgcn_rcpf(1.f + (float)eq[2] * (float)ek[2]);
        sg0.w = __builtin_amdgcn_rcpf(1.f + (float)eq[3] * (float)ek[3]);
        sg1.x = __builtin_amdgcn_rcpf(1.f + (float)eq[4] * (float)ek[4]);
        sg1.y = __builtin_amdgcn_rcpf(1.f + (float)eq[5] * (float)ek[5]);
        sg1.z = __builtin_amdgcn_rcpf(1.f + (float)eq[6] * (float)ek[6]);
        sg1.w = __builtin_amdgcn_rcpf(1.f + (float)eq[7] * (float)ek[7]);
        a4 += wv0 * sg0 + wv1 * sg1;
      }
      // 4 MFMAs for stage2 chunk c (separate pipe; overlaps score VALU)
      __builtin_amdgcn_s_setprio(1);
      acc2[0][0] = __builtin_amdgcn_mfma_f32_16x16x32_bf16(bcur0, af0, acc2[0][0], 0, 0, 0);
      acc2[0][1] = __builtin_amdgcn_mfma_f32_16x16x32_bf16(bcur1, af0, acc2[0][1], 0, 0, 0);
      acc2[1][0] = __builtin_amdgcn_mfma_f32_16x16x32_bf16(bcur0, af1, acc2[1][0], 0, 0, 0);
      acc2[1][1] = __builtin_amdgcn_mfma_f32_16x16x32_bf16(bcur1, af1, acc2[1][1], 0, 0, 0);
      __builtin_amdgcn_s_setprio(0);
      bcur0 = bnxt0; bcur1 = bnxt1;
    }
    // score reduction + diagonal softmax weight
    float s = (a4[0] + a4[1]) + (a4[2] + a4[3]);
    float m = s;
    for (int off = 8; off; off >>= 1) m = fmaxf(m, __shfl_xor(m, off, 16));
    const float e = __builtin_amdgcn_exp2f((s - m) * 1.4426950408889634f);
    float sum = e;
    for (int off = 8; off; off >>= 1) sum += __shfl_xor(sum, off, 16);
    if (kc == qc) af_s[p * 16 + qc] = e / sum;
  }
  __syncthreads();  // af_s visible to all waves

  // stage-2 epilogue: out = a*(acc2+bcomb)+bout, permuted (b,c,l,d) store
#pragma unroll
  for (int mi = 0; mi < 2; ++mi) {
    const int rl = mi * 16 + l15;
    const int r = rt0 + rl;
    const int c = r & 15, p = r >> 4;
    const int l = p & 511, b = p >> 9;
    const float av = af_s[rl];
    float* orow = out + ((size_t)(b * 16 + c) * 512 + l) * 256;
#pragma unroll
    for (int ni = 0; ni < 2; ++ni) {
      const int n = wave * 32 + ni * 16 + quad * 4;
      const float4 bc = *(const float4*)(bcomb + n);
      const float4 bo = *(const float4*)(bout + n);
      float4 o;
      o.x = fmaf(av, acc2[mi][ni][0] + bc.x, bo.x);
      o.y = fmaf(av, acc2[mi][ni][1] + bc.y, bo.y);
      o.z = fmaf(av, acc2[mi][ni][2] + bc.z, bo.z);
      o.w = fmaf(av, acc2[mi][ni][3] + bc.w, bo.w);
      *(float4*)(orow + n) = o;
    }
  }
}

extern "C" void kernel_launch(void* const* d_in, const int* in_sizes, int n_in,
                              void* d_out, int out_size, void* d_ws, size_t ws_size,
                              hipStream_t stream) {
  (void)in_sizes; (void)n_in; (void)out_size; (void)ws_size;
  const float* x    = (const float*)d_in[0];
  const float* Wqkv = (const float*)d_in[1];
  const float* bqkv = (const float*)d_in[2];
  const float* Vw   = (const float*)d_in[3];
  const float* bh   = (const float*)d_in[5];
  const float* Wout = (const float*)d_in[7];
  const float* bout = (const float*)d_in[8];
  float* out = (float*)d_out;

  // ws: bcomb fp32 256 | Wqb_t bf16 512*256 | Wcb_t bf16 256*256
  float* bcomb = (float*)d_ws;
  unsigned short* Wqb_t = (unsigned short*)(bcomb + 256);
  unsigned short* Wcb_t = Wqb_t + (size_t)512 * 256;

  ca_prep_kernel<<<dim3(320), dim3(256), 0, stream>>>(
      Wqkv, Wout, bqkv, Wqb_t, Wcb_t, bcomb);
  ca_fused<<<dim3(2048), dim3(512), 0, stream>>>(
      x, Wqb_t, Wcb_t, bqkv, bh, Vw, bcomb, bout, out);
}

// Round 10
// 190.575 us; speedup vs baseline: 1.5377x; 1.5377x over previous
//
#include <hip/hip_runtime.h>

// cAttention B=8, C=16, L=512, D=256 (fp32 in/out).
// R14 = R10 core (83us fused, best) + cvt_pk prologue (validated R12) +
//       bsc bias-precompute epilogue (validated R9). NO setprio.
// ATTRIBUTION (R10-R13 matrix): s_setprio inside the register-tight unrolled
// fused loop is the SPILL TRIGGER (R11+R13 both: WRITE 65->408MB scratch,
// fused ~2.2x slower). It fences code motion -> live ranges overlap past the
// 85-VGPR cap of __launch_bounds__(512,6). Rule: no sched fences in tight
// unrolled loops under hard occupancy bounds.
// Frozen: scalar-f32 score rcp(1+eq*ek) (R11 batched: spill-confounded;
// R12 packed-f16: +18us scheduling loss); full-exponent Es (clamp +-15 on
// 2z*log2e product).

typedef __attribute__((ext_vector_type(8))) short bf16x8;
typedef __attribute__((ext_vector_type(4))) float f32x4;
typedef __attribute__((ext_vector_type(8))) _Float16 h16x8;
typedef __attribute__((ext_vector_type(4))) _Float16 h16x4;
typedef const __attribute__((address_space(1))) void* gp1_t;
typedef __attribute__((address_space(3))) void* lp3_t;

__device__ __forceinline__ unsigned short f2bf(float f) {
  union { float f; unsigned int u; } v; v.f = f;
  return (unsigned short)((v.u + 0x7FFFu + ((v.u >> 16) & 1u)) >> 16);
}

__device__ __forceinline__ unsigned int cvt_pk_bf16(float a, float b) {
  unsigned int r;
  asm("v_cvt_pk_bf16_f32 %0, %1, %2" : "=v"(r) : "v"(a), "v"(b));
  return r;  // lo = bf16(a), hi = bf16(b)
}

// ---- prep: Wqb_t = transpose-pack(Wqkv[0:512]) ; Wcb_t = pack(Wout @ Wv) ;
//      bcomb = Wout @ bv ; bsc = (bqkv[0:512] + [bh,0]) * 2*log2(e).
//      W layout: W_t[k>>3][n][8] (8 consecutive k per 16B). ----
__global__ __launch_bounds__(256) void ca_prep_kernel(
    const float* __restrict__ Wqkv, const float* __restrict__ Wout,
    const float* __restrict__ bqkv, const float* __restrict__ bh,
    unsigned short* __restrict__ Wqb_t, unsigned short* __restrict__ Wcb_t,
    float* __restrict__ bcomb, float* __restrict__ bsc) {
  const int blk = blockIdx.x;
  if (blk < 64) {
    // convert+transpose Wqkv (512x256 f32) -> Wqb_t[k8][512][8] bf16
    const int t = blk * 256 + threadIdx.x;  // 16384 threads
    const int k8 = t >> 9, n = t & 511;
    const float* src = Wqkv + (size_t)n * 256 + k8 * 8;
    const float4 v0 = *(const float4*)src;
    const float4 v1 = *(const float4*)(src + 4);
    bf16x8 o;
    o[0] = (short)f2bf(v0.x); o[1] = (short)f2bf(v0.y);
    o[2] = (short)f2bf(v0.z); o[3] = (short)f2bf(v0.w);
    o[4] = (short)f2bf(v1.x); o[5] = (short)f2bf(v1.y);
    o[6] = (short)f2bf(v1.z); o[7] = (short)f2bf(v1.w);
    *(bf16x8*)(Wqb_t + (size_t)t * 8) = o;  // t = k8*512 + n: coalesced store
    return;
  }
  const int dp = blk - 64;       // output row n (0..255)
  const int e = threadIdx.x;     // k (0..255)
  if (dp < 2) {                  // bsc[512]: scaled combined bias
    const int n = dp * 256 + e;
    const float b = bqkv[n] + (n < 256 ? bh[n] : 0.f);
    bsc[n] = b * 2.8853900817779268f;  // 2*log2(e)
  }
  const float* wrow = Wout + (size_t)dp * 256;
  float acc = 0.f;
  for (int f = 0; f < 256; ++f)
    acc = fmaf(wrow[f], Wqkv[(size_t)(512 + f) * 256 + e], acc);
  Wcb_t[((size_t)(e >> 3) * 256 + dp) * 8 + (e & 7)] = f2bf(acc);
  if (e == 0) {
    float b = 0.f;
    for (int f = 0; f < 256; ++f) b = fmaf(wrow[f], bqkv[512 + f], b);
    bcomb[dp] = b;
  }
}

// ---- fused: qk MFMA + exp + (score || out MFMA) + softmax diag ----
__global__ __launch_bounds__(512, 6) void ca_fused(
    const float* __restrict__ x,               // (8,16,512,256) fp32
    const unsigned short* __restrict__ Wqb_t,  // [32][512][8] bf16
    const unsigned short* __restrict__ Wcb_t,  // [32][256][8] bf16
    const float* __restrict__ bsc,             // 512: (bias)*2log2e
    const float* __restrict__ Vw,
    const float* __restrict__ bcomb, const float* __restrict__ bout,
    float* __restrict__ out) {
  __shared__ __align__(16) unsigned short xs[32 * 264];  // 16.9 KB A tile
  __shared__ __align__(16) unsigned short BsEs[16640];   // 33.3 KB: Bs / Es alias
  __shared__ __align__(16) float vw_s[256];
  __shared__ float af_s[32];
  unsigned short* const Bs = BsEs;          // stage1 staging
  _Float16* const Es = (_Float16*)BsEs;     // 32 rows x 520 (512 + pad)

  const int tid = threadIdx.x;
  const int lane = tid & 63, wave = tid >> 6;
  const int quad = lane >> 4, l15 = lane & 15;
  const int rt0 = blockIdx.x * 32;          // global xf row base

  if (tid < 256) vw_s[tid] = -2.f * Vw[tid];

  // issue stage1 k0c=0 B loads (2048 x 16B segs, lane-linear into Bs)
#pragma unroll
  for (int i = 0; i < 4; ++i) {
    const int sb = wave * 256 + i * 64;
    const unsigned short* g = Wqb_t + (size_t)(sb + lane) * 8;
    __builtin_amdgcn_global_load_lds((gp1_t)g, (lp3_t)(Bs + sb * 8), 16, 0, 0);
  }

  // x tile: 32 rows x 256 fp32 -> bf16 -> xs (row stride 264: 2-way-free reads)
  {
    const int rl = tid >> 4, c0 = (tid & 15) * 16;
    const int r = rt0 + rl;
    const int b = r >> 13, l = (r >> 4) & 511, c = r & 15;
    const float* src = x + ((size_t)(b * 16 + c) * 512 + l) * 256 + c0;
    unsigned short* dst = xs + rl * 264 + c0;
#pragma unroll
    for (int j = 0; j < 2; ++j) {
      const float4 v0 = *(const float4*)(src + j * 8);
      const float4 v1 = *(const float4*)(src + j * 8 + 4);
      uint4 o;
      o.x = cvt_pk_bf16(v0.x, v0.y);
      o.y = cvt_pk_bf16(v0.z, v0.w);
      o.z = cvt_pk_bf16(v1.x, v1.y);
      o.w = cvt_pk_bf16(v1.z, v1.w);
      *(uint4*)(dst + j * 8) = o;
    }
  }
  __syncthreads();  // xs ready; k0c=0 B tile landed (barrier drains vmcnt)

  // ---------- stage 1: E[32 x 512] ----------
  f32x4 acc[2][4] = {};
  for (int k0c = 0; k0c < 8; ++k0c) {
    bf16x8 af[2], bfr[4];
#pragma unroll
    for (int mi = 0; mi < 2; ++mi)
      af[mi] = *(const bf16x8*)&xs[(mi * 16 + l15) * 264 + k0c * 32 + quad * 8];
#pragma unroll
    for (int ni = 0; ni < 4; ++ni)
      bfr[ni] = *(const bf16x8*)&Bs[(quad * 512 + wave * 64 + ni * 16 + l15) * 8];
    __syncthreads();  // frags in regs; Bs free for next tile
    if (k0c < 7) {
#pragma unroll
      for (int i = 0; i < 4; ++i) {
        const int sb = wave * 256 + i * 64;
        const unsigned short* g =
            Wqb_t + ((size_t)(k0c + 1) * 2048 + sb + lane) * 8;
        __builtin_amdgcn_global_load_lds((gp1_t)g, (lp3_t)(Bs + sb * 8), 16, 0, 0);
      }
    }
#pragma unroll
    for (int mi = 0; mi < 2; ++mi)
#pragma unroll
      for (int ni = 0; ni < 4; ++ni)
        acc[mi][ni] = __builtin_amdgcn_mfma_f32_16x16x32_bf16(
            bfr[ni], af[mi], acc[mi][ni], 0, 0, 0);
    __syncthreads();  // drains vmcnt: next tile ready
  }

  // stage-1 epilogue: E = exp2(clamp(acc*2log2e + bsc, +-15)) -> Es (over Bs)
  const float SC = 2.8853900817779268f;  // 2*log2(e)
#pragma unroll
  for (int mi = 0; mi < 2; ++mi) {
    const int rl = mi * 16 + l15;
#pragma unroll
    for (int ni = 0; ni < 4; ++ni) {
      const int n = wave * 64 + ni * 16 + quad * 4;
      const float4 bs = *(const float4*)(bsc + n);
      h16x4 st;
      st[0] = (_Float16)__builtin_amdgcn_exp2f(
          fminf(15.f, fmaxf(-15.f, fmaf(acc[mi][ni][0], SC, bs.x))));
      st[1] = (_Float16)__builtin_amdgcn_exp2f(
          fminf(15.f, fmaxf(-15.f, fmaf(acc[mi][ni][1], SC, bs.y))));
      st[2] = (_Float16)__builtin_amdgcn_exp2f(
          fminf(15.f, fmaxf(-15.f, fmaf(acc[mi][ni][2], SC, bs.z))));
      st[3] = (_Float16)__builtin_amdgcn_exp2f(
          fminf(15.f, fmaxf(-15.f, fmaf(acc[mi][ni][3], SC, bs.w))));
      *(h16x4*)&Es[rl * 520 + n] = st;
    }
  }
  __syncthreads();  // Es visible to all waves

  // ---------- fused: score (VALU) || stage 2 (MFMA + L2 B-fetch) ----------
  f32x4 acc2[2][2] = {};
  {
    const int p = tid >> 8, qc = (tid >> 4) & 15, kc = tid & 15;
    const _Float16* eqp = Es + (p * 16 + qc) * 520;
    const _Float16* ekp = Es + (p * 16 + kc) * 520 + 256;
    const unsigned short* wb2 = Wcb_t + (size_t)(quad * 256 + wave * 32 + l15) * 8;
    bf16x8 bcur0 = *(const bf16x8*)(wb2);
    bf16x8 bcur1 = *(const bf16x8*)(wb2 + 128);
    f32x4 a4 = {};
#pragma unroll
    for (int c = 0; c < 8; ++c) {
      bf16x8 bnxt0, bnxt1;
      if (c < 7) {  // prefetch next chunk's B-frags (covered by score VALU)
        bnxt0 = *(const bf16x8*)(wb2 + (size_t)(c + 1) * 8192);
        bnxt1 = *(const bf16x8*)(wb2 + (size_t)(c + 1) * 8192 + 128);
      }
      bf16x8 af0 = *(const bf16x8*)&xs[l15 * 264 + c * 32 + quad * 8];
      bf16x8 af1 = *(const bf16x8*)&xs[(16 + l15) * 264 + c * 32 + quad * 8];
      // 4 score iterations over d = 32c .. 32c+31 (scalar-f32 form: frozen)
#pragma unroll
      for (int j = 0; j < 4; ++j) {
        const int d = c * 32 + j * 8;
        const h16x8 eq = *(const h16x8*)(eqp + d);
        const h16x8 ek = *(const h16x8*)(ekp + d);
        const f32x4 wv0 = *(const f32x4*)(vw_s + d);
        const f32x4 wv1 = *(const f32x4*)(vw_s + d + 4);
        f32x4 sg0, sg1;
        sg0.x = __builtin_amdgcn_rcpf(1.f + (float)eq[0] * (float)ek[0]);
        sg0.y = __builtin_amdgcn_rcpf(1.f + (float)eq[1] * (float)ek[1]);
        sg0.z = __builtin_amdgcn_rcpf(1.f + (float)eq[2] * (float)ek[2]);
        sg0.w = __builtin_amdgcn_rcpf(1.f + (float)eq[3] * (float)ek[3]);
        sg1.x = __builtin_amdgcn_rcpf(1.f + (float)eq[4] * (float)ek[4]);
        sg1.y = __builtin_amdgcn_rcpf(1.f + (float)eq[5] * (float)ek[5]);
        sg1.z = __builtin_amdgcn_rcpf(1.f + (float)eq[6] * (float)ek[6]);
        sg1.w = __builtin_amdgcn_rcpf(1.f + (float)eq[7] * (float)ek[7]);
        a4 += wv0 * sg0 + wv1 * sg1;
      }
      // 4 MFMAs for stage2 chunk c (separate pipe; overlaps score VALU)
      acc2[0][0] = __builtin_amdgcn_mfma_f32_16x16x32_bf16(bcur0, af0, acc2[0][0], 0, 0, 0);
      acc2[0][1] = __builtin_amdgcn_mfma_f32_16x16x32_bf16(bcur1, af0, acc2[0][1], 0, 0, 0);
      acc2[1][0] = __builtin_amdgcn_mfma_f32_16x16x32_bf16(bcur0, af1, acc2[1][0], 0, 0, 0);
      acc2[1][1] = __builtin_amdgcn_mfma_f32_16x16x32_bf16(bcur1, af1, acc2[1][1], 0, 0, 0);
      bcur0 = bnxt0; bcur1 = bnxt1;
    }
    // score reduction + diagonal softmax weight
    float s = (a4[0] + a4[1]) + (a4[2] + a4[3]);
    float m = s;
    for (int off = 8; off; off >>= 1) m = fmaxf(m, __shfl_xor(m, off, 16));
    const float e = __builtin_amdgcn_exp2f((s - m) * 1.4426950408889634f);
    float sum = e;
    for (int off = 8; off; off >>= 1) sum += __shfl_xor(sum, off, 16);
    if (kc == qc) af_s[p * 16 + qc] = e / sum;
  }
  __syncthreads();  // af_s visible to all waves

  // stage-2 epilogue: out = a*(acc2+bcomb)+bout, permuted (b,c,l,d) store
#pragma unroll
  for (int mi = 0; mi < 2; ++mi) {
    const int rl = mi * 16 + l15;
    const int r = rt0 + rl;
    const int c = r & 15, p = r >> 4;
    const int l = p & 511, b = p >> 9;
    const float av = af_s[rl];
    float* orow = out + ((size_t)(b * 16 + c) * 512 + l) * 256;
#pragma unroll
    for (int ni = 0; ni < 2; ++ni) {
      const int n = wave * 32 + ni * 16 + quad * 4;
      const float4 bc = *(const float4*)(bcomb + n);
      const float4 bo = *(const float4*)(bout + n);
      float4 o;
      o.x = fmaf(av, acc2[mi][ni][0] + bc.x, bo.x);
      o.y = fmaf(av, acc2[mi][ni][1] + bc.y, bo.y);
      o.z = fmaf(av, acc2[mi][ni][2] + bc.z, bo.z);
      o.w = fmaf(av, acc2[mi][ni][3] + bc.w, bo.w);
      *(float4*)(orow + n) = o;
    }
  }
}

extern "C" void kernel_launch(void* const* d_in, const int* in_sizes, int n_in,
                              void* d_out, int out_size, void* d_ws, size_t ws_size,
                              hipStream_t stream) {
  (void)in_sizes; (void)n_in; (void)out_size; (void)ws_size;
  const float* x    = (const float*)d_in[0];
  const float* Wqkv = (const float*)d_in[1];
  const float* bqkv = (const float*)d_in[2];
  const float* Vw   = (const float*)d_in[3];
  const float* bh   = (const float*)d_in[5];
  const float* Wout = (const float*)d_in[7];
  const float* bout = (const float*)d_in[8];
  float* out = (float*)d_out;

  // ws: bcomb f32 256 | bsc f32 512 | Wqb_t bf16 512*256 | Wcb_t bf16 256*256
  float* bcomb = (float*)d_ws;
  float* bsc = bcomb + 256;
  unsigned short* Wqb_t = (unsigned short*)(bsc + 512);
  unsigned short* Wcb_t = Wqb_t + (size_t)512 * 256;

  ca_prep_kernel<<<dim3(320), dim3(256), 0, stream>>>(
      Wqkv, Wout, bqkv, bh, Wqb_t, Wcb_t, bcomb, bsc);
  ca_fused<<<dim3(2048), dim3(512), 0, stream>>>(
      x, Wqb_t, Wcb_t, bsc, Vw, bcomb, bout, out);
}